// Round 1
// baseline (180.038 us; speedup 1.0000x reference)
//
#include <hip/hip_runtime.h>
#include <hip/hip_bf16.h>
#include <stdint.h>

// Problem constants (from reference setup_inputs)
#define BATCH 8
#define TC 2048   // M
#define TQ 1024   // K
#define DD 1024   // N

typedef __attribute__((ext_vector_type(8))) __bf16 bf16x8;
typedef __attribute__((ext_vector_type(4))) float f32x4;

__device__ __forceinline__ ushort f2bf(float f) {
    uint32_t u = __float_as_uint(f);
    uint32_t r = (u + 0x7fffu + ((u >> 16) & 1u)) >> 16;  // RNE
    return (ushort)r;
}

// ---------------------------------------------------------------------------
// Kernel 1 (fused prep): blocks [0,4096) do wave-per-row softmax -> bf16 attn;
// blocks [4096,6144) do 64x64 transpose+cast of qencode -> qt.   (UNCHANGED)
// ---------------------------------------------------------------------------
__global__ __launch_bounds__(256) void prep(const float* __restrict__ sim,
                                            const float* __restrict__ qen,
                                            ushort* __restrict__ attn,
                                            ushort* __restrict__ qt) {
    __shared__ float tile[64][65];
    const int t = threadIdx.x;
    if (blockIdx.x < 4096) {
        // ---- softmax: one wave per row of 1024 ----
        const int wid = t >> 6;
        const int lane = t & 63;
        const int row = blockIdx.x * 4 + wid;
        const float4* src = (const float4*)(sim + (size_t)row * TQ);

        float4 x[4];
        #pragma unroll
        for (int j = 0; j < 4; j++) x[j] = src[lane + 64 * j];

        float m = -INFINITY;
        #pragma unroll
        for (int j = 0; j < 4; j++)
            m = fmaxf(m, fmaxf(fmaxf(x[j].x, x[j].y), fmaxf(x[j].z, x[j].w)));
        #pragma unroll
        for (int o = 32; o >= 1; o >>= 1) m = fmaxf(m, __shfl_xor(m, o));

        const float L2E = 1.4426950408889634f;
        float e[4][4];
        float s = 0.f;
        #pragma unroll
        for (int j = 0; j < 4; j++) {
            e[j][0] = exp2f((x[j].x - m) * L2E);
            e[j][1] = exp2f((x[j].y - m) * L2E);
            e[j][2] = exp2f((x[j].z - m) * L2E);
            e[j][3] = exp2f((x[j].w - m) * L2E);
            s += (e[j][0] + e[j][1]) + (e[j][2] + e[j][3]);
        }
        #pragma unroll
        for (int o = 32; o >= 1; o >>= 1) s += __shfl_xor(s, o);
        const float inv = 1.0f / s;

        ushort4* dst = (ushort4*)(attn + (size_t)row * TQ);
        #pragma unroll
        for (int j = 0; j < 4; j++) {
            ushort4 o4;
            o4.x = f2bf(e[j][0] * inv);
            o4.y = f2bf(e[j][1] * inv);
            o4.z = f2bf(e[j][2] * inv);
            o4.w = f2bf(e[j][3] * inv);
            dst[lane + 64 * j] = o4;
        }
    } else {
        // ---- transpose+cast: qencode [b][q][d] fp32 -> qt [b][d][q] bf16 ----
        const int bid = blockIdx.x - 4096;
        const int b = bid >> 8;             // 256 tiles per batch (16x16)
        const int rem = bid & 255;
        const int q0 = (rem >> 4) * 64;
        const int d0 = (rem & 15) * 64;
        const int r = t >> 4;               // 0..15
        const int c = (t & 15) * 4;         // 0..60

        #pragma unroll
        for (int it = 0; it < 4; it++) {
            float4 v = *(const float4*)(qen + ((size_t)b * TQ + q0 + r + it * 16) * DD + d0 + c);
            tile[r + it * 16][c + 0] = v.x;
            tile[r + it * 16][c + 1] = v.y;
            tile[r + it * 16][c + 2] = v.z;
            tile[r + it * 16][c + 3] = v.w;
        }
        __syncthreads();

        #pragma unroll
        for (int it = 0; it < 4; it++) {
            const int d = (t >> 4) + it * 16;
            const int qq = (t & 15) * 4;
            ushort4 o4;
            o4.x = f2bf(tile[qq + 0][d]);
            o4.y = f2bf(tile[qq + 1][d]);
            o4.z = f2bf(tile[qq + 2][d]);
            o4.w = f2bf(tile[qq + 3][d]);
            *(ushort4*)(qt + ((size_t)b * DD + d0 + d) * TQ + q0 + qq) = o4;
        }
    }
}

// ---------------------------------------------------------------------------
// Kernel 2: batched GEMM  C[b] = A[b] (MxK bf16) x Bt[b]^T (NxK bf16)
// 256x256 tile, BK=64, 8 waves (2m x 4n), 8-phase pipelined schedule
// (T2 swizzle + T3/T4 counted-vmcnt + T5 setprio).  128 KiB LDS, 1 block/CU,
// grid = 256 blocks = 8 batches x 8 m-tiles x 4 n-tiles; bijective swizzle
// maps one batch per XCD (B panel 2 MiB fits the 4 MiB XCD L2).
//
// LDS: As/Bs[buf][half][128 rows][64 k] bf16.  Chunk-XOR swizzle (carried from
// the verified 128^2 kernel): LDS slot (row, c) holds global 16B-chunk
// c ^ (row&7); staged with linear global_load_lds dest + pre-swizzled global
// source; frag read chunk = (ss*4+quad) ^ (l16&7)  -> conflict-free.
//
// Pipeline (iteration computes tiles T(buf0) ph1-4, T+1(buf1) ph5-8):
//   issue slots: ph3:(T+2).A0  ph4:(T+2).A1  ph5:(T+2).B0  ph6:(T+2).B1
//                ph7:(T+3).A0+A1  ph8:(T+3).B0+B1
//   waits: vmcnt(4) end of ph4 (retires T+1 fully before ph5 reads),
//          vmcnt(8) end of ph8 (retires T+2 fully before next ph1 reads).
//   Write-after-read safety: each half is re-staged >=1 barrier after its
//   last ds_read phase (A halves read ph1-2, staged ph3-4; B halves read
//   ph1&3, staged ph5+; buf1 mirrors at ph5-8).
//   Per phase: {ds_read frags | stage} ; s_barrier ; lgkmcnt(0) ;
//              setprio(1) ; 16 MFMA ; setprio(0) ; [vmcnt] ; s_barrier.
// ---------------------------------------------------------------------------
#define BAR()   __builtin_amdgcn_s_barrier()
#define LGKM0() asm volatile("s_waitcnt lgkmcnt(0)" ::: "memory")
#define PRIO(x) __builtin_amdgcn_s_setprio(x)

#define KTILE(BUF, S1, S2, S3, S4, WEND)                                           \
    {                                                                              \
        bf16x8 aLO[4][2], aHI[4][2], bLO[2][2], bHI[2][2];                         \
        /* ---- phase 1: A rows 0-63 of wave half + B n0-1 ---- */                 \
        _Pragma("unroll") for (int mi = 0; mi < 4; ++mi)                           \
            _Pragma("unroll") for (int ss = 0; ss < 2; ++ss)                       \
                aLO[mi][ss] = *(const bf16x8*)&As[BUF][wm][mi * 16 + l16]          \
                                  [((ss * 4 + quad) ^ rkey) * 8];                  \
        _Pragma("unroll") for (int ni = 0; ni < 2; ++ni)                           \
            _Pragma("unroll") for (int ss = 0; ss < 2; ++ss)                       \
                bLO[ni][ss] = *(const bf16x8*)&Bs[BUF][wbh][wrow + ni * 16 + l16]  \
                                  [((ss * 4 + quad) ^ rkey) * 8];                  \
        S1;                                                                        \
        BAR(); LGKM0(); PRIO(1);                                                   \
        _Pragma("unroll") for (int mi = 0; mi < 4; ++mi)                           \
            _Pragma("unroll") for (int ni = 0; ni < 2; ++ni)                       \
                _Pragma("unroll") for (int ss = 0; ss < 2; ++ss)                   \
                    acc[mi][ni] = __builtin_amdgcn_mfma_f32_16x16x32_bf16(         \
                        aLO[mi][ss], bLO[ni][ss], acc[mi][ni], 0, 0, 0);           \
        PRIO(0); BAR();                                                            \
        /* ---- phase 2: A rows 64-127 ---- */                                     \
        _Pragma("unroll") for (int mi = 0; mi < 4; ++mi)                           \
            _Pragma("unroll") for (int ss = 0; ss < 2; ++ss)                       \
                aHI[mi][ss] = *(const bf16x8*)&As[BUF][wm][64 + mi * 16 + l16]     \
                                  [((ss * 4 + quad) ^ rkey) * 8];                  \
        S2;                                                                        \
        BAR(); LGKM0(); PRIO(1);                                                   \
        _Pragma("unroll") for (int mi = 0; mi < 4; ++mi)                           \
            _Pragma("unroll") for (int ni = 0; ni < 2; ++ni)                       \
                _Pragma("unroll") for (int ss = 0; ss < 2; ++ss)                   \
                    acc[4 + mi][ni] = __builtin_amdgcn_mfma_f32_16x16x32_bf16(     \
                        aHI[mi][ss], bLO[ni][ss], acc[4 + mi][ni], 0, 0, 0);       \
        PRIO(0); BAR();                                                            \
        /* ---- phase 3: B n2-3 ---- */                                            \
        _Pragma("unroll") for (int ni = 0; ni < 2; ++ni)                           \
            _Pragma("unroll") for (int ss = 0; ss < 2; ++ss)                       \
                bHI[ni][ss] = *(const bf16x8*)&Bs[BUF][wbh]                        \
                                  [wrow + 32 + ni * 16 + l16]                      \
                                  [((ss * 4 + quad) ^ rkey) * 8];                  \
        S3;                                                                        \
        BAR(); LGKM0(); PRIO(1);                                                   \
        _Pragma("unroll") for (int mi = 0; mi < 4; ++mi)                           \
            _Pragma("unroll") for (int ni = 0; ni < 2; ++ni)                       \
                _Pragma("unroll") for (int ss = 0; ss < 2; ++ss)                   \
                    acc[mi][2 + ni] = __builtin_amdgcn_mfma_f32_16x16x32_bf16(     \
                        aLO[mi][ss], bHI[ni][ss], acc[mi][2 + ni], 0, 0, 0);       \
        PRIO(0); BAR();                                                            \
        /* ---- phase 4: no reads ---- */                                          \
        S4;                                                                        \
        BAR(); PRIO(1);                                                            \
        _Pragma("unroll") for (int mi = 0; mi < 4; ++mi)                           \
            _Pragma("unroll") for (int ni = 0; ni < 2; ++ni)                       \
                _Pragma("unroll") for (int ss = 0; ss < 2; ++ss)                   \
                    acc[4 + mi][2 + ni] = __builtin_amdgcn_mfma_f32_16x16x32_bf16( \
                        aHI[mi][ss], bHI[ni][ss], acc[4 + mi][2 + ni], 0, 0, 0);   \
        PRIO(0);                                                                   \
        WEND;                                                                      \
        BAR();                                                                     \
    }

__global__ __launch_bounds__(512, 2) void gemm_bf16(const ushort* __restrict__ A,
                                                    const ushort* __restrict__ Bt,
                                                    float* __restrict__ C) {
    __shared__ __align__(16) ushort As[2][2][128][64];   // 64 KiB
    __shared__ __align__(16) ushort Bs[2][2][128][64];   // 64 KiB

    // bijective XCD swizzle: 256 blocks, XCD x gets batch x (32 contiguous tiles)
    const int bid = blockIdx.x;
    const int swz = ((bid & 7) << 5) | (bid >> 3);
    const int b   = swz >> 5;
    const int tm0 = ((swz >> 2) & 7) * 256;
    const int tn0 = (swz & 3) * 256;

    const ushort* Ab = A + (size_t)b * TC * TQ;
    const ushort* Bb = Bt + (size_t)b * DD * TQ;
    float* Cb = C + (size_t)b * TC * DD;

    const int t = threadIdx.x;
    const int wid = t >> 6, lane = t & 63;
    const int quad = lane >> 4, l16 = lane & 15;
    const int wm = wid >> 2;          // 0..1  (m half)
    const int wn = wid & 3;           // 0..3  (n quarter)
    const int wbh = wn >> 1;          // B half this wave reads
    const int wrow = (wn & 1) << 6;   // row offset within B half
    const int rkey = l16 & 7;

    // staging: per thread, per half-tile: 2 x 16B loads.
    // load i covers LDS rows i*64 + (t>>3), chunk slot t&7; global chunk
    // pre-swizzled: (t&7) ^ ((t>>3)&7).
    const int srow = t >> 3;                         // 0..63
    const int gko  = (((t & 7) ^ (srow & 7)) << 3);  // ushort offset in k

    auto stageA = [&](int buf, int h, int kk) {
        const ushort* g0 = Ab + (size_t)(tm0 + h * 128 + srow) * TQ + kk + gko;
        char* l0 = (char*)(&As[buf][h][0][0]) + wid * 1024;
        __builtin_amdgcn_global_load_lds(
            (const __attribute__((address_space(1))) void*)g0,
            (__attribute__((address_space(3))) void*)l0, 16, 0, 0);
        __builtin_amdgcn_global_load_lds(
            (const __attribute__((address_space(1))) void*)(g0 + (size_t)64 * TQ),
            (__attribute__((address_space(3))) void*)(l0 + 8192), 16, 0, 0);
    };
    auto stageB = [&](int buf, int h, int kk) {
        const ushort* g0 = Bb + (size_t)(tn0 + h * 128 + srow) * TQ + kk + gko;
        char* l0 = (char*)(&Bs[buf][h][0][0]) + wid * 1024;
        __builtin_amdgcn_global_load_lds(
            (const __attribute__((address_space(1))) void*)g0,
            (__attribute__((address_space(3))) void*)l0, 16, 0, 0);
        __builtin_amdgcn_global_load_lds(
            (const __attribute__((address_space(1))) void*)(g0 + (size_t)64 * TQ),
            (__attribute__((address_space(3))) void*)(l0 + 8192), 16, 0, 0);
    };

    f32x4 acc[8][4];
    #pragma unroll
    for (int i = 0; i < 8; i++)
        #pragma unroll
        for (int j = 0; j < 4; j++) acc[i][j] = (f32x4){0.f, 0.f, 0.f, 0.f};

    // ---- prologue: stage tiles 0 (buf0) and 1 (buf1); retire tile 0 ----
    stageA(0, 0, 0);  stageA(0, 1, 0);  stageB(0, 0, 0);  stageB(0, 1, 0);
    stageA(1, 0, 64); stageA(1, 1, 64); stageB(1, 0, 64); stageB(1, 1, 64);
    asm volatile("s_waitcnt vmcnt(8)" ::: "memory");
    BAR();

    // ---- main loop: 7 iterations compute tiles 0..13, stage tiles 2..15 ----
    #pragma unroll 1
    for (int it = 0; it < 7; ++it) {
        const int kA = (2 * it + 2) * 64;   // k offset of tile T+2
        const int kB = (2 * it + 3) * 64;   // k offset of tile T+3
        KTILE(0,
              (void)0,
              (void)0,
              stageA(0, 0, kA),
              stageA(0, 1, kA),
              asm volatile("s_waitcnt vmcnt(4)" ::: "memory"));
        KTILE(1,
              stageB(0, 0, kA),
              stageB(0, 1, kA),
              (stageA(1, 0, kB), stageA(1, 1, kB)),
              (stageB(1, 0, kB), stageB(1, 1, kB)),
              asm volatile("s_waitcnt vmcnt(8)" ::: "memory"));
    }

    // ---- epilogue: tiles 14 (buf0) and 15 (buf1), no staging ----
    KTILE(0, (void)0, (void)0, (void)0, (void)0,
          asm volatile("s_waitcnt vmcnt(0)" ::: "memory"));
    KTILE(1, (void)0, (void)0, (void)0, (void)0, (void)0);

    // ---- C write: C/D layout col=l16, row=quad*4+reg ----
    #pragma unroll
    for (int mi = 0; mi < 8; ++mi) {
        const int r0 = tm0 + wm * 128 + mi * 16 + quad * 4;
        #pragma unroll
        for (int ni = 0; ni < 4; ++ni) {
            const int c = tn0 + wn * 64 + ni * 16 + l16;
            f32x4 v = acc[mi][ni];
            #pragma unroll
            for (int r = 0; r < 4; ++r) Cb[(size_t)(r0 + r) * DD + c] = v[r];
        }
    }
}

// ---------------------------------------------------------------------------
extern "C" void kernel_launch(void* const* d_in, const int* in_sizes, int n_in,
                              void* d_out, int out_size, void* d_ws, size_t ws_size,
                              hipStream_t stream) {
    const float* sim = (const float*)d_in[0];   // [8, 2048, 1024]
    const float* qen = (const float*)d_in[1];   // [8, 1024, 1024]
    float* out = (float*)d_out;                 // [8, 2048, 1024]

    ushort* attn = (ushort*)d_ws;                                  // 32 MiB bf16
    ushort* qt = (ushort*)d_ws + (size_t)BATCH * TC * TQ;          // 16 MiB bf16

    prep<<<4096 + 2048, 256, 0, stream>>>(sim, qen, attn, qt);
    gemm_bf16<<<BATCH * (TC / 256) * (DD / 256), 512, 0, stream>>>(attn, qt, out);
}